// Round 4
// baseline (226.327 us; speedup 1.0000x reference)
//
#include <hip/hip_runtime.h>
#include <hip/hip_bf16.h>
#include <stdint.h>
#include <stddef.h>

// MatchLSTMAttention: B=64, T=2048, inp_p=inp_q=out=512
// out[b] = concat(input_p[b], z[b]); z = softmax_t(w . tanh(prq[b] + iq[b,t] @ Wq^T)) @ iq[b]
// (match_b dropped: softmax is shift-invariant)

typedef __attribute__((ext_vector_type(8))) short short8;
typedef __attribute__((ext_vector_type(8))) unsigned short ushort8v;
typedef __attribute__((ext_vector_type(4))) float f32x4;

__device__ __forceinline__ unsigned short f2bf(float f) {
    unsigned int u = __builtin_bit_cast(unsigned int, f);
    return (unsigned short)((u + 0x7FFFu + ((u >> 16) & 1u)) >> 16);  // RNE (host-side-ish path, k_convert only)
}

__device__ __forceinline__ void gload_lds16(const void* g, void* l) {
    __builtin_amdgcn_global_load_lds(
        (const __attribute__((address_space(1))) unsigned int*)g,
        (__attribute__((address_space(3))) unsigned int*)l, 16, 0, 0);
}

// ---------- kernel Z: zero logits ----------
__global__ __launch_bounds__(256) void k_zero(float* __restrict__ p) {
    int i = (blockIdx.x * 256 + threadIdx.x) * 4;
    *(float4*)(p + i) = make_float4(0.f, 0.f, 0.f, 0.f);
}

// ---------- kernel 0: Wq fp32 -> bf16 ----------
__global__ __launch_bounds__(256) void k_convert(const float* __restrict__ Wq,
                                                 unsigned short* __restrict__ Wq_bf) {
    int i = (blockIdx.x * 256 + threadIdx.x) * 8;
    float4 a = *(const float4*)(Wq + i);
    float4 b = *(const float4*)(Wq + i + 4);
    ushort8v o;
    o[0] = f2bf(a.x); o[1] = f2bf(a.y); o[2] = f2bf(a.z); o[3] = f2bf(a.w);
    o[4] = f2bf(b.x); o[5] = f2bf(b.y); o[6] = f2bf(b.z); o[7] = f2bf(b.w);
    *(ushort8v*)(Wq_bf + i) = o;
}

// ---------- kernel 1: prq[b,o] = ip.Wp^T + h.Wr^T + bp + bq + br ----------
__global__ __launch_bounds__(256) void k_prq(
        const float* __restrict__ ip, const float* __restrict__ h,
        const float* __restrict__ Wp, const float* __restrict__ Wr,
        const float* __restrict__ bp, const float* __restrict__ bq,
        const float* __restrict__ br, float* __restrict__ prq) {
    __shared__ float ip_lds[64][68];
    __shared__ float h_lds[64][68];
    __shared__ float wp_lds[8][68];
    __shared__ float wr_lds[8][68];
    const int tid = threadIdx.x;
    const int o0 = blockIdx.x * 8;
    const int bb = tid >> 3;
    const int oo = tid & 7;
    float acc0 = 0.f, acc1 = 0.f;
    const int lrow = tid >> 2;
    const int lcol = (tid & 3) * 16;
    for (int kc = 0; kc < 512; kc += 64) {
        #pragma unroll
        for (int j = 0; j < 16; j += 4) {
            float4 v = *(const float4*)(ip + lrow * 512 + kc + lcol + j);
            ip_lds[lrow][lcol + j] = v.x; ip_lds[lrow][lcol + j + 1] = v.y;
            ip_lds[lrow][lcol + j + 2] = v.z; ip_lds[lrow][lcol + j + 3] = v.w;
            float4 u = *(const float4*)(h + lrow * 512 + kc + lcol + j);
            h_lds[lrow][lcol + j] = u.x; h_lds[lrow][lcol + j + 1] = u.y;
            h_lds[lrow][lcol + j + 2] = u.z; h_lds[lrow][lcol + j + 3] = u.w;
        }
        if (tid < 128) {
            int r = tid >> 4, c = (tid & 15) * 4;
            float4 v = *(const float4*)(Wp + (size_t)(o0 + r) * 512 + kc + c);
            wp_lds[r][c] = v.x; wp_lds[r][c + 1] = v.y; wp_lds[r][c + 2] = v.z; wp_lds[r][c + 3] = v.w;
        } else {
            int t2 = tid - 128;
            int r = t2 >> 4, c = (t2 & 15) * 4;
            float4 v = *(const float4*)(Wr + (size_t)(o0 + r) * 512 + kc + c);
            wr_lds[r][c] = v.x; wr_lds[r][c + 1] = v.y; wr_lds[r][c + 2] = v.z; wr_lds[r][c + 3] = v.w;
        }
        __syncthreads();
        #pragma unroll 4
        for (int k = 0; k < 64; ++k) {
            float wpv = wp_lds[oo][k], wrv = wr_lds[oo][k];
            acc0 += ip_lds[bb][k] * wpv + h_lds[bb][k] * wrv;
            acc1 += ip_lds[bb + 32][k] * wpv + h_lds[bb + 32][k] * wrv;
        }
        __syncthreads();
    }
    const int o = o0 + oo;
    float base = bp[o] + bq[o] + br[o];
    prq[bb * 512 + o] = acc0 + base;
    prq[(bb + 32) * 512 + o] = acc1 + base;
}

// ---------- kernel 2: fused Gq GEMM + tanh + w-reduction -> partial logits ----------
// 128x128 tile, 256 thr (4 waves of 64x64), BK=32.
// A: reg-staged fp32 -> v_cvt_pk_bf16_f32 -> ds_write_b64 into bf16 LDS (64B rows,
//    chunk ^= (row>>1)&3 swizzle, zero-conflict per R1). Next-step A loads issued
//    after the pre-compute barrier (latency hides under compute).
// B: global_load_lds w=16, pre-swizzled source (unchanged from R3, zero-conflict).
__global__ __launch_bounds__(256, 3) void k_gq(
        const float* __restrict__ iq, const unsigned short* __restrict__ Wq_bf,
        const float* __restrict__ prq, const float* __restrict__ wv,
        float* __restrict__ logits) {
    __shared__ unsigned short A_t[128][32];   // 8 KB
    __shared__ unsigned short B_t[128][32];   // 8 KB
    __shared__ float w_lds[128];
    __shared__ float prq_lds[128];
    __shared__ float red[2][128];

    const int tid = threadIdx.x;
    const int bid = blockIdx.x;
    const int orig = (bid & 7) * 512 + (bid >> 3);   // XCD-chunked (4096 % 8 == 0)
    const int m0 = (orig >> 2) * 128;
    const int n0 = (orig & 3) * 128;
    const int b = m0 >> 11;

    if (tid < 128) {
        w_lds[tid] = wv[n0 + tid];
        prq_lds[tid] = prq[b * 512 + n0 + tid];
    }

    const int lane = tid & 63;
    const int wave = tid >> 6;                // 0..3
    const int wm = wave >> 1;                 // 0..1 (m half)
    const int wn = wave & 1;                  // 0..1 (n half)
    const int r16 = lane & 15;
    const int cc = lane >> 4;                 // k-chunk 0..3 (16B)
    const int swz = ((cc ^ ((r16 >> 1) & 3)) << 3);  // read-side chunk offset (ushorts)

    // A staging: 4 rounds; round r: rows r*32 + (tid>>3), 16B fp32 (=4 floats) per lane.
    // Per-instr global pattern: 8 lanes cover one 128B row slice contiguously (coalesced).
    const int g4 = tid & 7;                   // 4-float group within the 32-float k-slice
    const float* asrc[4];
    unsigned short* adst[4];
    #pragma unroll
    for (int r = 0; r < 4; ++r) {
        int arow = r * 32 + (tid >> 3);
        asrc[r] = iq + (size_t)(m0 + arow) * 512 + g4 * 4;
        adst[r] = &A_t[arow][(((g4 >> 1) ^ ((arow >> 1) & 3)) << 3) + (g4 & 1) * 4];
    }

    // B staging (unchanged): source pre-swizzled, dest linear via global_load_lds.
    const unsigned short* bsrc[2];
    #pragma unroll
    for (int r = 0; r < 2; ++r) {
        int u = r * 256 + tid;
        int row = u >> 2, s = u & 3;
        bsrc[r] = Wq_bf + (size_t)(n0 + row) * 512 + ((s ^ ((row >> 1) & 3)) << 3);
    }
    char* bdst = (char*)B_t + wave * 1024;

    f32x4 acc[4][4];
    #pragma unroll
    for (int i = 0; i < 4; ++i)
        #pragma unroll
        for (int j = 0; j < 4; ++j) acc[i][j] = (f32x4){0.f, 0.f, 0.f, 0.f};

    float4 rA[4], rB[4];

#define LOADA(RN, K)                                   \
    RN[0] = *(const float4*)(asrc[0] + (K));           \
    RN[1] = *(const float4*)(asrc[1] + (K));           \
    RN[2] = *(const float4*)(asrc[2] + (K));           \
    RN[3] = *(const float4*)(asrc[3] + (K));

#define CVTW(RC, r)                                                              \
    {                                                                            \
        union { __hip_bfloat162 h[2]; uint2 v; } u_;                             \
        u_.h[0] = __float22bfloat162_rn(make_float2(RC[r].x, RC[r].y));          \
        u_.h[1] = __float22bfloat162_rn(make_float2(RC[r].z, RC[r].w));          \
        *(uint2*)adst[r] = u_.v;                                                 \
    }

#define STEP(K0, RC, RN, KN)                                                     \
    {                                                                            \
        __syncthreads();                                                         \
        CVTW(RC, 0) CVTW(RC, 1) CVTW(RC, 2) CVTW(RC, 3)                          \
        gload_lds16(bsrc[0] + (K0), bdst);                                       \
        gload_lds16(bsrc[1] + (K0), bdst + 4096);                                \
        __syncthreads();                                                         \
        LOADA(RN, KN);                                                           \
        short8 af[4];                                                            \
        af[0] = *(const short8*)&A_t[wm * 64 + 0 * 16 + r16][swz];               \
        af[1] = *(const short8*)&A_t[wm * 64 + 1 * 16 + r16][swz];               \
        af[2] = *(const short8*)&A_t[wm * 64 + 2 * 16 + r16][swz];               \
        af[3] = *(const short8*)&A_t[wm * 64 + 3 * 16 + r16][swz];               \
        _Pragma("unroll")                                                        \
        for (int nf = 0; nf < 4; ++nf) {                                         \
            short8 bfr = *(const short8*)&B_t[wn * 64 + nf * 16 + r16][swz];     \
            acc[0][nf] = __builtin_amdgcn_mfma_f32_16x16x32_bf16(af[0], bfr, acc[0][nf], 0, 0, 0); \
            acc[1][nf] = __builtin_amdgcn_mfma_f32_16x16x32_bf16(af[1], bfr, acc[1][nf], 0, 0, 0); \
            acc[2][nf] = __builtin_amdgcn_mfma_f32_16x16x32_bf16(af[2], bfr, acc[2][nf], 0, 0, 0); \
            acc[3][nf] = __builtin_amdgcn_mfma_f32_16x16x32_bf16(af[3], bfr, acc[3][nf], 0, 0, 0); \
        }                                                                        \
    }

    LOADA(rA, 0);
    for (int k0 = 0; k0 < 512; k0 += 64) {
        STEP(k0, rA, rB, k0 + 32);
        STEP(k0 + 32, rB, rA, (k0 + 64 < 512) ? (k0 + 64) : 480);
    }
#undef STEP
#undef CVTW
#undef LOADA

    // epilogue: partial logit = sum over this block's 128 cols of w[c]*tanh(acc+prq[c])
    float part[4][4];
    #pragma unroll
    for (int mf = 0; mf < 4; ++mf)
        #pragma unroll
        for (int j = 0; j < 4; ++j) part[mf][j] = 0.f;

    #pragma unroll
    for (int nf = 0; nf < 4; ++nf) {
        int c = wn * 64 + nf * 16 + r16;
        float wc = w_lds[c];
        float pc = prq_lds[c];
        #pragma unroll
        for (int mf = 0; mf < 4; ++mf) {
            #pragma unroll
            for (int j = 0; j < 4; ++j) {
                float x = acc[mf][nf][j] + pc;
                float e = __expf(2.f * x);               // fast tanh: 1 - 2/(e^2x + 1)
                part[mf][j] += wc * (1.f - 2.f / (e + 1.f));
            }
        }
    }
    #pragma unroll
    for (int mf = 0; mf < 4; ++mf)
        #pragma unroll
        for (int j = 0; j < 4; ++j) {
            float v = part[mf][j];
            v += __shfl_xor(v, 1);
            v += __shfl_xor(v, 2);
            v += __shfl_xor(v, 4);
            v += __shfl_xor(v, 8);
            part[mf][j] = v;
        }
    if (r16 == 0) {
        #pragma unroll
        for (int mf = 0; mf < 4; ++mf)
            #pragma unroll
            for (int j = 0; j < 4; ++j)
                red[wn][wm * 64 + mf * 16 + cc * 4 + j] = part[mf][j];
    }
    __syncthreads();
    if (tid < 128)
        atomicAdd(&logits[m0 + tid], red[0][tid] + red[1][tid]);
}

// ---------- kernel 3: softmax stats per b; copy input_p -> out; zero z ----------
__global__ __launch_bounds__(256) void k_stats(const float* __restrict__ logits,
                                               const float* __restrict__ ip,
                                               float* __restrict__ out,
                                               float* __restrict__ stats) {
    const int b = blockIdx.x, tid = threadIdx.x;
    __shared__ float sm[256];
    float m = -1e30f;
    for (int i = tid; i < 2048; i += 256) m = fmaxf(m, logits[b * 2048 + i]);
    sm[tid] = m;
    __syncthreads();
    for (int s = 128; s > 0; s >>= 1) {
        if (tid < s) sm[tid] = fmaxf(sm[tid], sm[tid + s]);
        __syncthreads();
    }
    float bmax = sm[0];
    __syncthreads();
    float ssum = 0.f;
    for (int i = tid; i < 2048; i += 256) ssum += __expf(logits[b * 2048 + i] - bmax);
    sm[tid] = ssum;
    __syncthreads();
    for (int s = 128; s > 0; s >>= 1) {
        if (tid < s) sm[tid] += sm[tid + s];
        __syncthreads();
    }
    if (tid == 0) { stats[b * 2] = bmax; stats[b * 2 + 1] = sm[0]; }
    out[b * 1024 + tid] = ip[b * 512 + tid];
    out[b * 1024 + 256 + tid] = ip[b * 512 + 256 + tid];
    out[b * 1024 + 512 + tid] = 0.f;
    out[b * 1024 + 768 + tid] = 0.f;
}

// ---------- kernel 4: z[b,q] += sum_t alpha[b,t] * iq[b,t,q] ----------
#define TC 128
__global__ __launch_bounds__(256) void k_z(const float* __restrict__ logits,
                                           const float* __restrict__ stats,
                                           const float* __restrict__ iq,
                                           float* __restrict__ out) {
    const int blk = blockIdx.x;
    const int b = blk >> 4;
    const int c = blk & 15;
    const int tid = threadIdx.x;
    __shared__ float al[TC];
    const float bmax = stats[b * 2];
    const float inv = 1.f / stats[b * 2 + 1];
    if (tid < TC) al[tid] = __expf(logits[b * 2048 + c * TC + tid] - bmax) * inv;
    __syncthreads();
    const int q = tid * 2;
    float ax = 0.f, ay = 0.f;
    const float* base = iq + ((size_t)b * 2048 + (size_t)c * TC) * 512 + q;
    #pragma unroll 4
    for (int t = 0; t < TC; ++t) {
        float2 v = *(const float2*)(base + (size_t)t * 512);
        float a = al[t];
        ax += a * v.x;
        ay += a * v.y;
    }
    atomicAdd(&out[b * 1024 + 512 + q], ax);
    atomicAdd(&out[b * 1024 + 512 + q + 1], ay);
}

extern "C" void kernel_launch(void* const* d_in, const int* in_sizes, int n_in,
                              void* d_out, int out_size, void* d_ws, size_t ws_size,
                              hipStream_t stream) {
    const float* input_p = (const float*)d_in[0];
    const float* input_q = (const float*)d_in[1];
    const float* h_tm1   = (const float*)d_in[2];
    const float* Wp      = (const float*)d_in[3];
    const float* bp      = (const float*)d_in[4];
    const float* Wq      = (const float*)d_in[5];
    const float* bq      = (const float*)d_in[6];
    const float* Wr      = (const float*)d_in[7];
    const float* br      = (const float*)d_in[8];
    const float* wv      = (const float*)d_in[9];
    float* out = (float*)d_out;

    char* ws = (char*)d_ws;
    unsigned short* Wq_bf = (unsigned short*)ws;            // 512 KB
    float* prq    = (float*)(ws + 512 * 1024);              // 128 KB
    float* logits = (float*)(ws + 640 * 1024);              // 512 KB
    float* stats  = (float*)(ws + 1152 * 1024);             // 512 B

    k_zero<<<dim3(128), dim3(256), 0, stream>>>(logits);
    k_convert<<<dim3(128), dim3(256), 0, stream>>>(Wq, Wq_bf);
    k_prq<<<dim3(64), dim3(256), 0, stream>>>(input_p, h_tm1, Wp, Wr, bp, bq, br, prq);
    k_gq<<<dim3(4096), dim3(256), 0, stream>>>(input_q, Wq_bf, prq, wv, logits);
    k_stats<<<dim3(64), dim3(256), 0, stream>>>(logits, input_p, out, stats);
    k_z<<<dim3(64 * 16), dim3(256), 0, stream>>>(logits, stats, input_q, out);
}

// Round 5
// 205.796 us; speedup vs baseline: 1.0998x; 1.0998x over previous
//
#include <hip/hip_runtime.h>
#include <hip/hip_bf16.h>
#include <stdint.h>
#include <stddef.h>

// MatchLSTMAttention: B=64, T=2048, inp_p=inp_q=out=512
// out[b] = concat(input_p[b], z[b]); z = softmax_t(w . tanh(prq[b] + iq[b,t] @ Wq^T)) @ iq[b]

typedef __attribute__((ext_vector_type(8))) short short8;
typedef __attribute__((ext_vector_type(8))) unsigned short ushort8v;
typedef __attribute__((ext_vector_type(4))) float f32x4;

__device__ __forceinline__ unsigned short f2bf(float f) {
    unsigned int u = __builtin_bit_cast(unsigned int, f);
    return (unsigned short)((u + 0x7FFFu + ((u >> 16) & 1u)) >> 16);  // RNE
}

__device__ __forceinline__ void gload_lds16(const void* g, void* l) {
    __builtin_amdgcn_global_load_lds(
        (const __attribute__((address_space(1))) unsigned int*)g,
        (__attribute__((address_space(3))) unsigned int*)l, 16, 0, 0);
}

__device__ __forceinline__ short8 cvt8(float4 a, float4 b) {
    union { __hip_bfloat162 h[4]; short8 s; } u;
    u.h[0] = __float22bfloat162_rn(make_float2(a.x, a.y));
    u.h[1] = __float22bfloat162_rn(make_float2(a.z, a.w));
    u.h[2] = __float22bfloat162_rn(make_float2(b.x, b.y));
    u.h[3] = __float22bfloat162_rn(make_float2(b.z, b.w));
    return u.s;
}

// ---------- kernel Z: zero logits ----------
__global__ __launch_bounds__(256) void k_zero(float* __restrict__ p) {
    int i = (blockIdx.x * 256 + threadIdx.x) * 4;
    *(float4*)(p + i) = make_float4(0.f, 0.f, 0.f, 0.f);
}

// ---------- kernel 0: Wq fp32 -> bf16 ----------
__global__ __launch_bounds__(256) void k_convert(const float* __restrict__ Wq,
                                                 unsigned short* __restrict__ Wq_bf) {
    int i = (blockIdx.x * 256 + threadIdx.x) * 8;
    float4 a = *(const float4*)(Wq + i);
    float4 b = *(const float4*)(Wq + i + 4);
    ushort8v o;
    o[0] = f2bf(a.x); o[1] = f2bf(a.y); o[2] = f2bf(a.z); o[3] = f2bf(a.w);
    o[4] = f2bf(b.x); o[5] = f2bf(b.y); o[6] = f2bf(b.z); o[7] = f2bf(b.w);
    *(ushort8v*)(Wq_bf + i) = o;
}

// ---------- kernel 1: prq[b,o] = ip.Wp^T + h.Wr^T + bp + bq + br ----------
__global__ __launch_bounds__(256) void k_prq(
        const float* __restrict__ ip, const float* __restrict__ h,
        const float* __restrict__ Wp, const float* __restrict__ Wr,
        const float* __restrict__ bp, const float* __restrict__ bq,
        const float* __restrict__ br, float* __restrict__ prq) {
    __shared__ float ip_lds[64][68];
    __shared__ float h_lds[64][68];
    __shared__ float wp_lds[8][68];
    __shared__ float wr_lds[8][68];
    const int tid = threadIdx.x;
    const int o0 = blockIdx.x * 8;
    const int bb = tid >> 3;
    const int oo = tid & 7;
    float acc0 = 0.f, acc1 = 0.f;
    const int lrow = tid >> 2;
    const int lcol = (tid & 3) * 16;
    for (int kc = 0; kc < 512; kc += 64) {
        #pragma unroll
        for (int j = 0; j < 16; j += 4) {
            float4 v = *(const float4*)(ip + lrow * 512 + kc + lcol + j);
            ip_lds[lrow][lcol + j] = v.x; ip_lds[lrow][lcol + j + 1] = v.y;
            ip_lds[lrow][lcol + j + 2] = v.z; ip_lds[lrow][lcol + j + 3] = v.w;
            float4 u = *(const float4*)(h + lrow * 512 + kc + lcol + j);
            h_lds[lrow][lcol + j] = u.x; h_lds[lrow][lcol + j + 1] = u.y;
            h_lds[lrow][lcol + j + 2] = u.z; h_lds[lrow][lcol + j + 3] = u.w;
        }
        if (tid < 128) {
            int r = tid >> 4, c = (tid & 15) * 4;
            float4 v = *(const float4*)(Wp + (size_t)(o0 + r) * 512 + kc + c);
            wp_lds[r][c] = v.x; wp_lds[r][c + 1] = v.y; wp_lds[r][c + 2] = v.z; wp_lds[r][c + 3] = v.w;
        } else {
            int t2 = tid - 128;
            int r = t2 >> 4, c = (t2 & 15) * 4;
            float4 v = *(const float4*)(Wr + (size_t)(o0 + r) * 512 + kc + c);
            wr_lds[r][c] = v.x; wr_lds[r][c + 1] = v.y; wr_lds[r][c + 2] = v.z; wr_lds[r][c + 3] = v.w;
        }
        __syncthreads();
        #pragma unroll 4
        for (int k = 0; k < 64; ++k) {
            float wpv = wp_lds[oo][k], wrv = wr_lds[oo][k];
            acc0 += ip_lds[bb][k] * wpv + h_lds[bb][k] * wrv;
            acc1 += ip_lds[bb + 32][k] * wpv + h_lds[bb + 32][k] * wrv;
        }
        __syncthreads();
    }
    const int o = o0 + oo;
    float base = bp[o] + bq[o] + br[o];
    prq[bb * 512 + o] = acc0 + base;
    prq[(bb + 32) * 512 + o] = acc1 + base;
}

// ---------- kernel 2: fused Gq GEMM + tanh + w-reduction -> partial logits ----------
// 128x128 tile, 4 waves (64x64 each), BK=32, DOUBLE-BUFFERED 2-phase pipeline:
// one raw s_barrier per K-step; stage(k+1) issued at top of step k (B: global_load_lds
// pre-swizzled source; A: reg loads -> cvt_pk -> swizzled ds_write after compute);
// explicit s_waitcnt vmcnt(0) lgkmcnt(0) before the barrier (counted-wait discipline).
__global__ __launch_bounds__(256, 3) void k_gq(
        const float* __restrict__ iq, const unsigned short* __restrict__ Wq_bf,
        const float* __restrict__ prq, const float* __restrict__ wv,
        float* __restrict__ logits) {
    __shared__ unsigned short A2[2][4096];    // 2 x 8 KB bf16, 64B rows, chunk^=(row>>1)&3
    __shared__ unsigned short B2[2][4096];    // 2 x 8 KB
    __shared__ float w_lds[128];
    __shared__ float prq_lds[128];
    __shared__ float red[2][128];

    const int tid = threadIdx.x;
    const int bid = blockIdx.x;
    const int orig = (bid & 7) * 512 + (bid >> 3);   // XCD-chunked (4096 % 8 == 0)
    const int m0 = (orig >> 2) * 128;
    const int n0 = (orig & 3) * 128;
    const int b = m0 >> 11;

    if (tid < 128) {
        w_lds[tid] = wv[n0 + tid];
        prq_lds[tid] = prq[b * 512 + n0 + tid];
    }

    const int lane = tid & 63;
    const int wave = tid >> 6;
    const int wm = wave >> 1;
    const int wn = wave & 1;
    const int r16 = lane & 15;
    const int cc = lane >> 4;
    const int swz = ((cc ^ ((r16 >> 1) & 3)) << 3);

    // A staging: 2 tasks/thread of (row, 8-float chunk); write one swizzled b128 each.
    const int ar0 = tid >> 2, ac0 = tid & 3;
    const int ar1 = 64 + (tid >> 2), ac1 = tid & 3;
    const float* asrc0 = iq + (size_t)(m0 + ar0) * 512 + ac0 * 8;
    const float* asrc1 = iq + (size_t)(m0 + ar1) * 512 + ac1 * 8;
    const int aoff0 = ar0 * 32 + ((ac0 ^ ((ar0 >> 1) & 3)) << 3);
    const int aoff1 = ar1 * 32 + ((ac1 ^ ((ar1 >> 1) & 3)) << 3);

    // B staging: pre-swizzled global source, linear LDS dest via global_load_lds.
    const int brw0 = tid >> 2, bs0 = (tid & 3) ^ ((brw0 >> 1) & 3);
    const int brw1 = 64 + (tid >> 2);
    const int bs1 = (tid & 3) ^ ((brw1 >> 1) & 3);
    const unsigned short* bsrc0 = Wq_bf + (size_t)(n0 + brw0) * 512 + (bs0 << 3);
    const unsigned short* bsrc1 = Wq_bf + (size_t)(n0 + brw1) * 512 + (bs1 << 3);

    f32x4 acc[4][4];
    #pragma unroll
    for (int i = 0; i < 4; ++i)
        #pragma unroll
        for (int j = 0; j < 4; ++j) acc[i][j] = (f32x4){0.f, 0.f, 0.f, 0.f};

    float4 ra0, ra1, ra2, ra3;

    // prologue: stage k=0 into buffer 0
    gload_lds16(bsrc0, (char*)&B2[0][0] + wave * 1024);
    gload_lds16(bsrc1, (char*)&B2[0][0] + 4096 + wave * 1024);
    ra0 = *(const float4*)(asrc0);
    ra1 = *(const float4*)(asrc0 + 4);
    ra2 = *(const float4*)(asrc1);
    ra3 = *(const float4*)(asrc1 + 4);
    *(short8*)&A2[0][aoff0] = cvt8(ra0, ra1);
    *(short8*)&A2[0][aoff1] = cvt8(ra2, ra3);
    asm volatile("s_waitcnt vmcnt(0) lgkmcnt(0)" ::: "memory");
    __builtin_amdgcn_sched_barrier(0);
    __builtin_amdgcn_s_barrier();

#define PHASE(K, C, PF)                                                          \
    {                                                                            \
        if (PF) {                                                                \
            gload_lds16(bsrc0 + (K) + 32, (char*)&B2[(C) ^ 1][0] + wave * 1024); \
            gload_lds16(bsrc1 + (K) + 32, (char*)&B2[(C) ^ 1][0] + 4096 + wave * 1024); \
            ra0 = *(const float4*)(asrc0 + (K) + 32);                            \
            ra1 = *(const float4*)(asrc0 + (K) + 36);                            \
            ra2 = *(const float4*)(asrc1 + (K) + 32);                            \
            ra3 = *(const float4*)(asrc1 + (K) + 36);                            \
        }                                                                        \
        short8 af0 = *(const short8*)&A2[C][(wm * 64 +  0 + r16) * 32 + swz];    \
        short8 af1 = *(const short8*)&A2[C][(wm * 64 + 16 + r16) * 32 + swz];    \
        short8 af2 = *(const short8*)&A2[C][(wm * 64 + 32 + r16) * 32 + swz];    \
        short8 af3 = *(const short8*)&A2[C][(wm * 64 + 48 + r16) * 32 + swz];    \
        _Pragma("unroll")                                                        \
        for (int nf = 0; nf < 4; ++nf) {                                         \
            short8 bfr = *(const short8*)&B2[C][(wn * 64 + nf * 16 + r16) * 32 + swz]; \
            acc[0][nf] = __builtin_amdgcn_mfma_f32_16x16x32_bf16(af0, bfr, acc[0][nf], 0, 0, 0); \
            acc[1][nf] = __builtin_amdgcn_mfma_f32_16x16x32_bf16(af1, bfr, acc[1][nf], 0, 0, 0); \
            acc[2][nf] = __builtin_amdgcn_mfma_f32_16x16x32_bf16(af2, bfr, acc[2][nf], 0, 0, 0); \
            acc[3][nf] = __builtin_amdgcn_mfma_f32_16x16x32_bf16(af3, bfr, acc[3][nf], 0, 0, 0); \
        }                                                                        \
        if (PF) {                                                                \
            *(short8*)&A2[(C) ^ 1][aoff0] = cvt8(ra0, ra1);                      \
            *(short8*)&A2[(C) ^ 1][aoff1] = cvt8(ra2, ra3);                      \
        }                                                                        \
        asm volatile("s_waitcnt vmcnt(0) lgkmcnt(0)" ::: "memory");              \
        __builtin_amdgcn_sched_barrier(0);                                       \
        __builtin_amdgcn_s_barrier();                                            \
    }

    for (int kk = 0; kk < 512; kk += 64) {
        PHASE(kk, 0, 1);
        PHASE(kk + 32, 1, (kk + 64) < 512);
    }
#undef PHASE

    // epilogue: partial logit = sum over this block's 128 cols of w[c]*tanh(acc+prq[c])
    float part[4][4];
    #pragma unroll
    for (int mf = 0; mf < 4; ++mf)
        #pragma unroll
        for (int j = 0; j < 4; ++j) part[mf][j] = 0.f;

    #pragma unroll
    for (int nf = 0; nf < 4; ++nf) {
        int c = wn * 64 + nf * 16 + r16;
        float wc = w_lds[c];
        float pc = prq_lds[c];
        #pragma unroll
        for (int mf = 0; mf < 4; ++mf) {
            #pragma unroll
            for (int j = 0; j < 4; ++j) {
                float x = acc[mf][nf][j] + pc;
                float e = __expf(2.f * x);               // fast tanh: 1 - 2/(e^2x + 1)
                part[mf][j] += wc * (1.f - 2.f / (e + 1.f));
            }
        }
    }
    #pragma unroll
    for (int mf = 0; mf < 4; ++mf)
        #pragma unroll
        for (int j = 0; j < 4; ++j) {
            float v = part[mf][j];
            v += __shfl_xor(v, 1);
            v += __shfl_xor(v, 2);
            v += __shfl_xor(v, 4);
            v += __shfl_xor(v, 8);
            part[mf][j] = v;
        }
    if (r16 == 0) {
        #pragma unroll
        for (int mf = 0; mf < 4; ++mf)
            #pragma unroll
            for (int j = 0; j < 4; ++j)
                red[wn][wm * 64 + mf * 16 + cc * 4 + j] = part[mf][j];
    }
    __syncthreads();
    if (tid < 128)
        atomicAdd(&logits[m0 + tid], red[0][tid] + red[1][tid]);
}

// ---------- kernel 3: softmax stats per b; copy input_p -> out; zero z ----------
__global__ __launch_bounds__(256) void k_stats(const float* __restrict__ logits,
                                               const float* __restrict__ ip,
                                               float* __restrict__ out,
                                               float* __restrict__ stats) {
    const int b = blockIdx.x, tid = threadIdx.x;
    __shared__ float sm[256];
    float m = -1e30f;
    for (int i = tid; i < 2048; i += 256) m = fmaxf(m, logits[b * 2048 + i]);
    sm[tid] = m;
    __syncthreads();
    for (int s = 128; s > 0; s >>= 1) {
        if (tid < s) sm[tid] = fmaxf(sm[tid], sm[tid + s]);
        __syncthreads();
    }
    float bmax = sm[0];
    __syncthreads();
    float ssum = 0.f;
    for (int i = tid; i < 2048; i += 256) ssum += __expf(logits[b * 2048 + i] - bmax);
    sm[tid] = ssum;
    __syncthreads();
    for (int s = 128; s > 0; s >>= 1) {
        if (tid < s) sm[tid] += sm[tid + s];
        __syncthreads();
    }
    if (tid == 0) { stats[b * 2] = bmax; stats[b * 2 + 1] = sm[0]; }
    out[b * 1024 + tid] = ip[b * 512 + tid];
    out[b * 1024 + 256 + tid] = ip[b * 512 + 256 + tid];
    out[b * 1024 + 512 + tid] = 0.f;
    out[b * 1024 + 768 + tid] = 0.f;
}

// ---------- kernel 4: z[b,q] += sum_t alpha[b,t] * iq[b,t,q] ----------
#define TC 128
__global__ __launch_bounds__(256) void k_z(const float* __restrict__ logits,
                                           const float* __restrict__ stats,
                                           const float* __restrict__ iq,
                                           float* __restrict__ out) {
    const int blk = blockIdx.x;
    const int b = blk >> 4;
    const int c = blk & 15;
    const int tid = threadIdx.x;
    __shared__ float al[TC];
    const float bmax = stats[b * 2];
    const float inv = 1.f / stats[b * 2 + 1];
    if (tid < TC) al[tid] = __expf(logits[b * 2048 + c * TC + tid] - bmax) * inv;
    __syncthreads();
    const int q = tid * 2;
    float ax = 0.f, ay = 0.f;
    const float* base = iq + ((size_t)b * 2048 + (size_t)c * TC) * 512 + q;
    #pragma unroll 4
    for (int t = 0; t < TC; ++t) {
        float2 v = *(const float2*)(base + (size_t)t * 512);
        float a = al[t];
        ax += a * v.x;
        ay += a * v.y;
    }
    atomicAdd(&out[b * 1024 + 512 + q], ax);
    atomicAdd(&out[b * 1024 + 512 + q + 1], ay);
}

extern "C" void kernel_launch(void* const* d_in, const int* in_sizes, int n_in,
                              void* d_out, int out_size, void* d_ws, size_t ws_size,
                              hipStream_t stream) {
    const float* input_p = (const float*)d_in[0];
    const float* input_q = (const float*)d_in[1];
    const float* h_tm1   = (const float*)d_in[2];
    const float* Wp      = (const float*)d_in[3];
    const float* bp      = (const float*)d_in[4];
    const float* Wq      = (const float*)d_in[5];
    const float* bq      = (const float*)d_in[6];
    const float* Wr      = (const float*)d_in[7];
    const float* br      = (const float*)d_in[8];
    const float* wv      = (const float*)d_in[9];
    float* out = (float*)d_out;

    char* ws = (char*)d_ws;
    unsigned short* Wq_bf = (unsigned short*)ws;            // 512 KB
    float* prq    = (float*)(ws + 512 * 1024);              // 128 KB
    float* logits = (float*)(ws + 640 * 1024);              // 512 KB
    float* stats  = (float*)(ws + 1152 * 1024);             // 512 B

    k_zero<<<dim3(128), dim3(256), 0, stream>>>(logits);
    k_convert<<<dim3(128), dim3(256), 0, stream>>>(Wq, Wq_bf);
    k_prq<<<dim3(64), dim3(256), 0, stream>>>(input_p, h_tm1, Wp, Wr, bp, bq, br, prq);
    k_gq<<<dim3(4096), dim3(256), 0, stream>>>(input_q, Wq_bf, prq, wv, logits);
    k_stats<<<dim3(64), dim3(256), 0, stream>>>(logits, input_p, out, stats);
    k_z<<<dim3(64 * 16), dim3(256), 0, stream>>>(logits, stats, input_q, out);
}